// Round 8
// baseline (234.234 us; speedup 1.0000x reference)
//
#include <hip/hip_runtime.h>

// EmbedDNF: B=128, IN_F=256, HID=512, OUT=128, E=8 (fp32, e innermost)
//
// impl = 1 - w*(1-xnor) = A + x*Bv ; A = 1 - w*s ; Bv = 2*w*s - w
// H[b,h,e]   = prod_i (A[i,h,e] + x[b,i,e]*Bv[i,h,e])
// out[b,o,e] = 1 - prod_h (1 - dw[h,o,e]*H[b,h,e])
//
// Laws (R4-R18): (1) acc <= 32 VGPR; (2) no device-scope fences; (3) >= 4
// blocks/CU, and stage1 must keep 32 waves/CU (<=64 VGPR, <=16 KB LDS,
// grid 2048) — R15/R16: halving occupancy costs ~5 us, cancels any gain;
// (4) latency-bound (VALUBusy ~4%); (5) R17 LESSON: VMEM traffic, line
// count, and per-wave MLP all falsified as s1's binding term (halving each
// was neutral). Remaining big modeled term: LDS ISSUE SLOTS — broadcast
// ds_read_b128 costs ~12 cy/instr while returning 32 useful bytes;
// R14-s1 = 80 b128/wave = 12.8 us/CU of LDS pipe. R17 grew reads -> +2 us
// (positive check).
// Ledger (R0-R17): best 89.2 (R14) = fill ~43 (harness poison, in-window,
// untouchable) + s1 ~30 + s2 ~13 + comb2 ~3.
// This round (R18): s1 redesign — h = full 64-lane dim, 8e+4b in registers,
// x becomes WAVE-UNIFORM -> scalar loads (SMEM pipe) via readfirstlane'd
// base. Inner loop: 4 dwordx4 VMEM (w,s) + scalar x + 88 VALU, ZERO LDS.
// kc-combine shrinks to 16 b128/thread (LDS 80 -> 16 wave-ops; barriers
// 6 -> 4). Accepted cost: w/s L2 traffic 128->256 MB (R17: traffic
// doesn't bind). launch_bounds(256,8) pins <=64 VGPR. s2/comb2 unchanged.
//
// ws: P1 [8][512][128][8] fp32 @ 0        (16 MB)  stage1 i-split partials
//     P2 [16][128][128][8] fp32 @ 4194304 (8 MB)   stage2 h-split partials

#define LD4(p) (*(const float4*)(p))

static __device__ __forceinline__ float4 f4mul(float4 a, float4 b) {
    return make_float4(a.x*b.x, a.y*b.y, a.z*b.z, a.w*b.w);
}
static __device__ __forceinline__ float4 f4fma(float4 a, float4 b, float4 c) {
    return make_float4(fmaf(a.x,b.x,c.x), fmaf(a.y,b.y,c.y),
                       fmaf(a.z,b.z,c.z), fmaf(a.w,b.w,c.w));
}
static __device__ __forceinline__ float4 f4nfma1(float4 d, float4 h) {  // 1-d*h
    return make_float4(fmaf(-d.x,h.x,1.0f), fmaf(-d.y,h.y,1.0f),
                       fmaf(-d.z,h.z,1.0f), fmaf(-d.w,h.w,1.0f));
}

// ---------------------------------------------------------------------------
// Stage 1 (R18). Grid 2048. Decode: bits[1:0]=hg01, [2]=ks0, [3]=hg2,
// [5:4]=ks12, [10:6]=bg. XCD = bid&7 = (hg&3)|(ks&1)<<2 -> per-XCD hot
// cw/cs slice = 2 hg x 4 ks = 128h x 128i x 2 arrays = 1 MB, 32x bg L2
// reuse. Block 256 = 4 waves (kc = i-subchunk of 8); lane = h (64 h/wave,
// h-tile 64). Thread tile 4b x 8e = acc[4][2] float4 = 32 VGPR.
// Step: 4 streaming dwordx4 (w,s: lane-stride 32 B) + 8 wave-uniform
// scalar x-loads (SMEM pipe, readfirstlane base) + ~88 VALU. 8 steps.
// NO LDS, NO barrier before epilogue. kc-combine: 2 phases of 2 b via
// 16 KB LDS ([kc4][bl2][hf2] chunks x 64 lanes x 16 B), 16 b128/thread
// total, 4 barriers. launch_bounds(256,8): <=64 VGPR -> 8 blocks/CU.
// ---------------------------------------------------------------------------
__global__ __launch_bounds__(256, 8) void k_stage1(
    const float* __restrict__ in,   // [128][256][8]
    const float* __restrict__ cw,   // [256][512][8]
    const float* __restrict__ cs,   // [256][512][8]
    float* __restrict__ P1)         // ws: [8][512][128][8]
{
    __shared__ float lds[4096];              // 16 KB: kc-combine only
    const int t    = threadIdx.x;
    const int l    = t & 63;                 // h-lane
    const int kc   = t >> 6;                 // 0..3 (i-subchunk)
    const int bid  = blockIdx.x;
    const int hg   = (bid & 3) | (((bid >> 3) & 1) << 2);        // 0..7
    const int ks   = ((bid >> 2) & 1) | (((bid >> 4) & 3) << 1); // 0..7
    const int bg   = bid >> 6;                                   // 0..31
    const int b0   = bg * 4;
    const int h    = hg * 64 + l;

    const int i0   = ks * 32 + kc * 8;
    const float* pw = cw + i0 * 4096 + h * 8;
    const float* ps = cs + i0 * 4096 + h * 8;
    // wave-uniform x base (scalar): x[b0..b0+4][i0..i0+8][0..8]
    const float* xs = in + __builtin_amdgcn_readfirstlane(b0 * 2048 + i0 * 8);

    float4 acc[4][2];
    #pragma unroll
    for (int b = 0; b < 4; ++b) {
        acc[b][0] = make_float4(1.f, 1.f, 1.f, 1.f);
        acc[b][1] = make_float4(1.f, 1.f, 1.f, 1.f);
    }

    #pragma unroll
    for (int ii = 0; ii < 8; ++ii) {
        const float4 w0 = LD4(pw);     const float4 w1 = LD4(pw + 4);
        const float4 s0 = LD4(ps);     const float4 s1 = LD4(ps + 4);
        pw += 4096; ps += 4096;
        const float4 p0 = f4mul(w0, s0);
        const float4 p1 = f4mul(w1, s1);
        const float4 A0 = make_float4(1.f - p0.x, 1.f - p0.y, 1.f - p0.z, 1.f - p0.w);
        const float4 A1 = make_float4(1.f - p1.x, 1.f - p1.y, 1.f - p1.z, 1.f - p1.w);
        const float4 B0 = make_float4(fmaf(2.f, p0.x, -w0.x), fmaf(2.f, p0.y, -w0.y),
                                      fmaf(2.f, p0.z, -w0.z), fmaf(2.f, p0.w, -w0.w));
        const float4 B1 = make_float4(fmaf(2.f, p1.x, -w1.x), fmaf(2.f, p1.y, -w1.y),
                                      fmaf(2.f, p1.z, -w1.z), fmaf(2.f, p1.w, -w1.w));
        #pragma unroll
        for (int b = 0; b < 4; ++b) {
            const float4 xa = LD4(xs + b * 2048 + ii * 8);      // scalar loads
            const float4 xb = LD4(xs + b * 2048 + ii * 8 + 4);
            acc[b][0] = f4mul(acc[b][0], f4fma(xa, B0, A0));
            acc[b][1] = f4mul(acc[b][1], f4fma(xb, B1, A1));
        }
    }

    // kc-combine: 2 phases of 2 b. Chunk layout: [(kc*2+bl)*2+hf][l] x 16 B.
    #pragma unroll
    for (int ph = 0; ph < 2; ++ph) {
        __syncthreads();                     // protect prior phase reads
        #pragma unroll
        for (int bl = 0; bl < 2; ++bl)
            #pragma unroll
            for (int hf = 0; hf < 2; ++hf)
                *(float4*)&lds[((kc * 2 + bl) * 2 + hf) * 256 + l * 4]
                    = acc[ph * 2 + bl][hf];
        __syncthreads();
        {   // thread t -> (l2, bl, hf); multiply 4 kc chunks; coalesced P1 store
            const int l2 = t >> 2;
            const int bl = (t >> 1) & 1;
            const int hf = t & 1;
            const int base = (bl * 2 + hf) * 256 + l2 * 4;
            float4 m = LD4(&lds[base]);
            #pragma unroll
            for (int c = 1; c < 4; ++c)
                m = f4mul(m, LD4(&lds[c * 1024 + base]));
            *(float4*)(P1 + ks * 524288 + (hg * 64 + l2) * 1024
                          + (b0 + ph * 2 + bl) * 8 + hf * 4) = m;
        }
    }
}

// ---------------------------------------------------------------------------
// Stage 2 (R11 structure, R13 remap — UNCHANGED). Grid 1024 = ks16 (low
// bits: XCD = ks&7 pins P1 h-slices + dw slice in L2) x og4 x bg16.
// Block 256 = 4 waves; lane = eh2 x ol32; thread tile 8b x 1o x 4e.
// ---------------------------------------------------------------------------
__global__ __launch_bounds__(256, 4) void k_stage2(
    const float* __restrict__ dw,   // [512][128][8]
    const float* __restrict__ P1,   // ws: [8][512][128][8]
    float* __restrict__ P2)         // ws: [16][128][128][8]
{
    __shared__ float lds[4096];              // 16 KB: H-tile [0,2048) then combine
    const int t    = threadIdx.x;
    const int lane = t & 63;
    const int kc   = t >> 6;                 // 0..3
    const int eh   = lane & 1;
    const int ol   = lane >> 1;              // 0..31
    const int ks   = blockIdx.x & 15;        // LOW bits: XCD = ks&7
    const int og   = (blockIdx.x >> 4) & 3;
    const int bg   = blockIdx.x >> 6;        // 0..15
    const int b0   = bg * 8;
    const int o    = og * 32 + ol;
    const int e0   = eh * 4;
    const int h0   = ks * 32;

    // H-tile: product of the 8 i-split partials, layout [hl][b][e]
    {
        float4* ht4 = (float4*)lds;
        #pragma unroll
        for (int k = 0; k < 2; ++k) {
            const int f4  = t + k * 256;     // 0..511
            const int hl  = f4 >> 4;
            const int rem = f4 & 15;         // b*2 + eq
            const float* q = P1 + (h0 + hl) * 1024 + b0 * 8 + rem * 4;
            float4 m = LD4(q);
            #pragma unroll
            for (int c = 1; c < 8; ++c) m = f4mul(m, LD4(q + c * 524288));
            ht4[f4] = m;
        }
    }
    __syncthreads();

    const float* pd = dw + (h0 + kc * 8) * 1024 + o * 8 + e0;
    const float* hbase = lds + kc * 512 + e0;   // + ii*64 + b*8 (immediates)

    float4 acc[8];
    #pragma unroll
    for (int b = 0; b < 8; ++b) acc[b] = make_float4(1.f, 1.f, 1.f, 1.f);

    #pragma unroll
    for (int ii = 0; ii < 8; ++ii) {
        const float4 dv = LD4(pd);
        pd += 1024;
        #pragma unroll
        for (int b = 0; b < 8; ++b) {
            const float4 hv = LD4(hbase + ii * 64 + b * 8);
            acc[b] = f4mul(acc[b], f4nfma1(dv, hv));
        }
    }

    __syncthreads();                         // H-tile dead; reuse lds
    // 2 phases of 4 b: partial[kc][j4][ol32][e8] = 1024 floats per kc
    #pragma unroll
    for (int phase = 0; phase < 2; ++phase) {
        if (phase) __syncthreads();
        #pragma unroll
        for (int j = 0; j < 4; ++j)
            *(float4*)&lds[kc * 1024 + j * 256 + ol * 8 + e0] = acc[phase * 4 + j];
        __syncthreads();
        {
            const int o4 = t * 4;            // j*256 + ol2*8 + eq*4
            float4 m = LD4(&lds[o4]);
            #pragma unroll
            for (int c = 1; c < 4; ++c) m = f4mul(m, LD4(&lds[c * 1024 + o4]));
            const int j   = o4 >> 8;
            const int ol2 = (o4 >> 3) & 31;
            const int eq  = o4 & 7;
            *(float4*)(P2 + ks * 131072 + (b0 + phase * 4 + j) * 1024
                          + (og * 32 + ol2) * 8 + eq) = m;
        }
    }
}

// ---------------------------------------------------------------------------
// Final: out = 1 - prod over the 16 h-split partials. 8 MB read, 0.5 MB write.
// 16 independent loads per thread -> deep MLP. UNCHANGED.
// ---------------------------------------------------------------------------
__global__ __launch_bounds__(256, 4) void k_comb2(
    const float* __restrict__ P2,   // ws: [16][128][128][8]
    float* __restrict__ out)        // [128][128][8]
{
    const int idx4 = blockIdx.x * 256 + threadIdx.x;   // 0..32767
    float4 m = LD4(P2 + idx4 * 4);
    #pragma unroll
    for (int c = 1; c < 16; ++c)
        m = f4mul(m, LD4(P2 + c * 131072 + idx4 * 4));
    const float4 r = make_float4(1.f - m.x, 1.f - m.y, 1.f - m.z, 1.f - m.w);
    *(float4*)(out + idx4 * 4) = r;
}

extern "C" void kernel_launch(void* const* d_in, const int* in_sizes, int n_in,
                              void* d_out, int out_size, void* d_ws, size_t ws_size,
                              hipStream_t stream)
{
    const float* in = (const float*)d_in[0];   // [128][256][8]
    const float* cw = (const float*)d_in[1];   // [256][512][8]
    const float* cs = (const float*)d_in[2];   // [256][512][8]
    const float* dw = (const float*)d_in[3];   // [512][128][8]
    float* outp = (float*)d_out;               // [128][128][8]
    float* P1   = (float*)d_ws;                // 16 MB
    float* P2   = (float*)d_ws + 4194304;      // 8 MB

    k_stage1<<<2048, 256, 0, stream>>>(in, cw, cs, P1);
    k_stage2<<<1024, 256, 0, stream>>>(dw, P1, P2);
    k_comb2<<<128, 256, 0, stream>>>(P2, outp);
}

// Round 9
// 88.627 us; speedup vs baseline: 2.6429x; 2.6429x over previous
//
#include <hip/hip_runtime.h>

// EmbedDNF: B=128, IN_F=256, HID=512, OUT=128, E=8 (fp32, e innermost)
//
// impl = 1 - w*(1-xnor) = A + x*Bv ; A = 1 - w*s ; Bv = 2*w*s - w
// H[b,h,e]   = prod_i (A[i,h,e] + x[b,i,e]*Bv[i,h,e])
// out[b,o,e] = 1 - prod_h (1 - dw[h,o,e]*H[b,h,e])
//
// Laws (R4-R19): (1) acc <= 32 VGPR; (2) broadcast operands in LDS —
// R18 PROVED the x-tile LDS staging is what keeps s1's VMEM stream small
// and L2-resident (removing it: FETCH 242 MB, WRITE 325 MB, 163 us);
// (3) no device-scope fences; (4) >= 4 blocks/CU, s1 at 32 waves/CU
// (<=64 VGPR, <=16 KB LDS, grid 2048); (5) latency-bound (VALUBusy ~4%);
// (6) falsified s1 levers: per-wave MLP (R15), VMEM traffic (R16/R17),
// LDS issue count (R17/R18). Only winning family: latency-class /
// XCD-L2-pinning blockIdx remaps (R13 s2 -2, R14 s1 -5).
// Ledger: best 89.2 (R14) = fill ~43 (harness poison, in-window,
// untouchable) + s1 ~30 + s2 ~13 + comb2 ~3.
// This round (R19): pure revert to R14 (byte-identical) after R18's
// 234 us disaster — secure the optimum, re-sample the baseline.
//
// ws: P1 [8][512][128][8] fp32 @ 0        (16 MB)  stage1 i-split partials
//     P2 [16][128][128][8] fp32 @ 4194304 (8 MB)   stage2 h-split partials

#define LD4(p) (*(const float4*)(p))

static __device__ __forceinline__ float4 f4mul(float4 a, float4 b) {
    return make_float4(a.x*b.x, a.y*b.y, a.z*b.z, a.w*b.w);
}
static __device__ __forceinline__ float4 f4fma(float4 a, float4 b, float4 c) {
    return make_float4(fmaf(a.x,b.x,c.x), fmaf(a.y,b.y,c.y),
                       fmaf(a.z,b.z,c.z), fmaf(a.w,b.w,c.w));
}
static __device__ __forceinline__ float4 f4nfma1(float4 d, float4 h) {  // 1-d*h
    return make_float4(fmaf(-d.x,h.x,1.0f), fmaf(-d.y,h.y,1.0f),
                       fmaf(-d.z,h.z,1.0f), fmaf(-d.w,h.w,1.0f));
}

// ---------------------------------------------------------------------------
// Stage 1 (R14, best). Grid 2048. Decode: bits [1:0]=hg-lo, [2]=ks-lo,
// [4:3]=hg-hi, [6:5]=ks-hi, [10:7]=bg. XCD = bid&7 = (hg&3)|(ks&1)<<2:
// per XCD hg in {a,a+4,a+8,a+12} (128 h), ks in {b,b+2,b+4,b+6} (128 i),
// all bg -> hot cw/cs set 1 MB, 16x L2 reuse. Block 256 = 4 waves = 4
// i-subchunks of 8. Lane = eh2 x hl32; thread tile 8b x 1h x 4e
// (acc = 32 VGPR, R7-proven).
// ---------------------------------------------------------------------------
__global__ __launch_bounds__(256, 4) void k_stage1(
    const float* __restrict__ in,   // [128][256][8]
    const float* __restrict__ cw,   // [256][512][8]
    const float* __restrict__ cs,   // [256][512][8]
    float* __restrict__ P1)         // ws: [8][512][128][8]
{
    __shared__ float lds[4096];              // 16 KB: x-tile [0,2048) then combine
    const int t    = threadIdx.x;
    const int lane = t & 63;
    const int kc   = t >> 6;                 // 0..3
    const int eh   = lane & 1;
    const int hl   = lane >> 1;              // 0..31
    const int bid  = blockIdx.x;
    const int hg   = (bid & 3) | (((bid >> 3) & 3) << 2);    // 0..15
    const int ks   = ((bid >> 2) & 1) | (((bid >> 5) & 3) << 1); // 0..7
    const int bg   = bid >> 7;                               // 0..15
    const int b0   = bg * 8;
    const int h    = hg * 32 + hl;
    const int e0   = eh * 4;

    // stage x[b0:+8][ks*32:+32][0:8] -> lds (layout [b][il][e]), coalesced
    {
        float4* xs4 = (float4*)lds;
        #pragma unroll
        for (int k = 0; k < 2; ++k) {
            const int f4  = t + k * 256;     // 0..511
            const int b   = f4 >> 6;
            const int col = f4 & 63;         // float4 within 256-float row
            xs4[f4] = LD4(in + (b0 + b) * 2048 + ks * 256 + col * 4);
        }
    }
    __syncthreads();

    const int i0 = ks * 32 + kc * 8;
    const float* pw = cw + i0 * 4096 + h * 8 + e0;
    const float* ps = cs + i0 * 4096 + h * 8 + e0;
    const float* xbase = lds + kc * 64 + e0;    // + b*256 + ii*8 (immediates)

    float4 acc[8];
    #pragma unroll
    for (int b = 0; b < 8; ++b) acc[b] = make_float4(1.f, 1.f, 1.f, 1.f);

    #pragma unroll
    for (int ii = 0; ii < 8; ++ii) {
        const float4 wv = LD4(pw);
        const float4 sv = LD4(ps);
        pw += 4096; ps += 4096;
        const float4 p  = f4mul(wv, sv);
        const float4 A  = make_float4(1.f - p.x, 1.f - p.y, 1.f - p.z, 1.f - p.w);
        const float4 Bv = make_float4(fmaf(2.f, p.x, -wv.x), fmaf(2.f, p.y, -wv.y),
                                      fmaf(2.f, p.z, -wv.z), fmaf(2.f, p.w, -wv.w));
        #pragma unroll
        for (int b = 0; b < 8; ++b) {
            const float4 xv = LD4(xbase + b * 256 + ii * 8);
            acc[b] = f4mul(acc[b], f4fma(xv, Bv, A));
        }
    }

    __syncthreads();                         // x-tile dead; reuse lds
    #pragma unroll
    for (int phase = 0; phase < 2; ++phase) {
        if (phase) __syncthreads();          // protect phase-0 reads
        #pragma unroll
        for (int j = 0; j < 4; ++j)
            *(float4*)&lds[kc * 1024 + j * 256 + hl * 8 + e0] = acc[phase * 4 + j];
        __syncthreads();
        {   // combine 4 kc; thread t -> one float4 of the 1024-float tile
            const int o4 = t * 4;            // j*256 + hl2*8 + eq*4
            float4 m = LD4(&lds[o4]);
            #pragma unroll
            for (int c = 1; c < 4; ++c) m = f4mul(m, LD4(&lds[c * 1024 + o4]));
            const int j   = o4 >> 8;
            const int hl2 = (o4 >> 3) & 31;
            const int eq  = o4 & 7;          // 0 or 4
            *(float4*)(P1 + ks * 524288 + (hg * 32 + hl2) * 1024
                          + (b0 + phase * 4 + j) * 8 + eq) = m;
        }
    }
}

// ---------------------------------------------------------------------------
// Stage 2 (R11 structure, R13 remap). Grid 1024 = ks16 (low bits:
// XCD = ks&7 pins P1 h-slices + dw slice in L2) x og4 x bg16.
// Block 256 = 4 waves; lane = eh2 x ol32; thread tile 8b x 1o x 4e.
// ---------------------------------------------------------------------------
__global__ __launch_bounds__(256, 4) void k_stage2(
    const float* __restrict__ dw,   // [512][128][8]
    const float* __restrict__ P1,   // ws: [8][512][128][8]
    float* __restrict__ P2)         // ws: [16][128][128][8]
{
    __shared__ float lds[4096];              // 16 KB: H-tile [0,2048) then combine
    const int t    = threadIdx.x;
    const int lane = t & 63;
    const int kc   = t >> 6;                 // 0..3
    const int eh   = lane & 1;
    const int ol   = lane >> 1;              // 0..31
    const int ks   = blockIdx.x & 15;        // LOW bits: XCD = ks&7
    const int og   = (blockIdx.x >> 4) & 3;
    const int bg   = blockIdx.x >> 6;        // 0..15
    const int b0   = bg * 8;
    const int o    = og * 32 + ol;
    const int e0   = eh * 4;
    const int h0   = ks * 32;

    // H-tile: product of the 8 i-split partials, layout [hl][b][e]
    {
        float4* ht4 = (float4*)lds;
        #pragma unroll
        for (int k = 0; k < 2; ++k) {
            const int f4  = t + k * 256;     // 0..511
            const int hl  = f4 >> 4;
            const int rem = f4 & 15;         // b*2 + eq
            const float* q = P1 + (h0 + hl) * 1024 + b0 * 8 + rem * 4;
            float4 m = LD4(q);
            #pragma unroll
            for (int c = 1; c < 8; ++c) m = f4mul(m, LD4(q + c * 524288));
            ht4[f4] = m;
        }
    }
    __syncthreads();

    const float* pd = dw + (h0 + kc * 8) * 1024 + o * 8 + e0;
    const float* hbase = lds + kc * 512 + e0;   // + ii*64 + b*8 (immediates)

    float4 acc[8];
    #pragma unroll
    for (int b = 0; b < 8; ++b) acc[b] = make_float4(1.f, 1.f, 1.f, 1.f);

    #pragma unroll
    for (int ii = 0; ii < 8; ++ii) {
        const float4 dv = LD4(pd);
        pd += 1024;
        #pragma unroll
        for (int b = 0; b < 8; ++b) {
            const float4 hv = LD4(hbase + ii * 64 + b * 8);
            acc[b] = f4mul(acc[b], f4nfma1(dv, hv));
        }
    }

    __syncthreads();                         // H-tile dead; reuse lds
    // 2 phases of 4 b: partial[kc][j4][ol32][e8] = 1024 floats per kc
    #pragma unroll
    for (int phase = 0; phase < 2; ++phase) {
        if (phase) __syncthreads();
        #pragma unroll
        for (int j = 0; j < 4; ++j)
            *(float4*)&lds[kc * 1024 + j * 256 + ol * 8 + e0] = acc[phase * 4 + j];
        __syncthreads();
        {
            const int o4 = t * 4;            // j*256 + ol2*8 + eq*4
            float4 m = LD4(&lds[o4]);
            #pragma unroll
            for (int c = 1; c < 4; ++c) m = f4mul(m, LD4(&lds[c * 1024 + o4]));
            const int j   = o4 >> 8;
            const int ol2 = (o4 >> 3) & 31;
            const int eq  = o4 & 7;
            *(float4*)(P2 + ks * 131072 + (b0 + phase * 4 + j) * 1024
                          + (og * 32 + ol2) * 8 + eq) = m;
        }
    }
}

// ---------------------------------------------------------------------------
// Final: out = 1 - prod over the 16 h-split partials. 8 MB read, 0.5 MB write.
// 16 independent loads per thread -> deep MLP.
// ---------------------------------------------------------------------------
__global__ __launch_bounds__(256, 4) void k_comb2(
    const float* __restrict__ P2,   // ws: [16][128][128][8]
    float* __restrict__ out)        // [128][128][8]
{
    const int idx4 = blockIdx.x * 256 + threadIdx.x;   // 0..32767
    float4 m = LD4(P2 + idx4 * 4);
    #pragma unroll
    for (int c = 1; c < 16; ++c)
        m = f4mul(m, LD4(P2 + c * 131072 + idx4 * 4));
    const float4 r = make_float4(1.f - m.x, 1.f - m.y, 1.f - m.z, 1.f - m.w);
    *(float4*)(out + idx4 * 4) = r;
}

extern "C" void kernel_launch(void* const* d_in, const int* in_sizes, int n_in,
                              void* d_out, int out_size, void* d_ws, size_t ws_size,
                              hipStream_t stream)
{
    const float* in = (const float*)d_in[0];   // [128][256][8]
    const float* cw = (const float*)d_in[1];   // [256][512][8]
    const float* cs = (const float*)d_in[2];   // [256][512][8]
    const float* dw = (const float*)d_in[3];   // [512][128][8]
    float* outp = (float*)d_out;               // [128][128][8]
    float* P1   = (float*)d_ws;                // 16 MB
    float* P2   = (float*)d_ws + 4194304;      // 8 MB

    k_stage1<<<2048, 256, 0, stream>>>(in, cw, cs, P1);
    k_stage2<<<1024, 256, 0, stream>>>(dw, P1, P2);
    k_comb2<<<128, 256, 0, stream>>>(P2, outp);
}